// Round 2
// baseline (637.873 us; speedup 1.0000x reference)
//
#include <hip/hip_runtime.h>
#include <hip/hip_bf16.h>

// Problem constants
// B=8 IC=8 ID=16 OC=8 OD=16 H=W=32 K=3 ITER=3
// conv: xf (64, 64, 32, 32) * tw (512, 64, 3, 3) -> p (64, 512, 32, 32)
// BN channel c = co4>>2 (128 channels), routing per (b, r, y, x)
// v output: (B, OC, OD, 4, H, W) = 4,194,304 fp32; entropy scalar at out[4194304]

__device__ inline float bf2f(unsigned int u) {
    union { unsigned int i; float f; } x;
    x.i = u << 16;
    return x.f;
}
__device__ inline unsigned short f2bf(float f) {
    union { float f; unsigned int u; } x;
    x.f = f;
    unsigned int r = x.u + 0x7fffu + ((x.u >> 16) & 1u);
    return (unsigned short)(r >> 16);
}

// ---------------- kernel 1: build transformed weights ----------------
// twl[ci4][tap][co4] : [64][9][512] fp32
__global__ __launch_bounds__(256) void k_tw(const float* __restrict__ w,
                                            float* __restrict__ twl) {
    int idx = blockIdx.x * 256 + threadIdx.x;
    if (idx >= 64 * 9 * 512) return;
    int co4 = idx & 511;
    int tap = (idx >> 9) % 9;
    int ci4 = idx / (9 * 512);
    int r = co4 & 3, co = co4 >> 2;
    int s = ci4 & 3, ci = ci4 >> 2;
    int ky = tap / 3, kx = tap % 3;
    int sy, sx;
    switch (r) {
        case 0: sy = ky;      sx = kx;      break;
        case 1: sy = kx;      sx = 2 - ky;  break;
        case 2: sy = 2 - ky;  sx = 2 - kx;  break;
        default: sy = 2 - kx; sx = ky;      break;
    }
    int ss = (s - r) & 3;
    twl[idx] = w[(((co * 16 + ci) * 4 + ss) * 3 + sy) * 3 + sx];
}

// ---------------- kernel 2: conv (fp32 compute, bf16 out) ----------------
// grid (64 n, 8 ytile, 4 cot), block 256 = (x 32, cg 8)
// thread computes 4 y rows x 16 co4 channels
#define CI_CHUNK 8
__global__ __launch_bounds__(256) void k_conv(const float* __restrict__ xf,
                                              const float* __restrict__ twl,
                                              unsigned short* __restrict__ p) {
    int n = blockIdx.x, yt = blockIdx.y, cot = blockIdx.z;
    int y0 = yt * 4;
    int x = threadIdx.x & 31, cg = threadIdx.x >> 5;
    int co_base = cot * 128 + cg * 16;

    __shared__ float xs[6][CI_CHUNK][34];
    __shared__ float wl[CI_CHUNK][9][128];

    float acc[4][16];
#pragma unroll
    for (int a = 0; a < 4; ++a)
#pragma unroll
        for (int b = 0; b < 16; ++b) acc[a][b] = 0.f;

    for (int ch = 0; ch < 8; ++ch) {
        __syncthreads();
        // stage x rows y0-1 .. y0+4, zero padded
        for (int t = threadIdx.x; t < 6 * CI_CHUNK * 34; t += 256) {
            int row = t / (CI_CHUNK * 34);
            int rem = t % (CI_CHUNK * 34);
            int cil = rem / 34;
            int xx = rem % 34;
            int gy = y0 - 1 + row, gx = xx - 1;
            int ci4 = ch * CI_CHUNK + cil;
            float v = 0.f;
            if ((unsigned)gy < 32u && (unsigned)gx < 32u)
                v = xf[((n * 64 + ci4) * 32 + gy) * 32 + gx];
            xs[row][cil][xx] = v;
        }
        // stage weights for this (ci chunk, co tile)
        for (int t = threadIdx.x; t < CI_CHUNK * 9 * 128; t += 256) {
            int cil = t / (9 * 128);
            int rem = t % (9 * 128);
            int tap = rem >> 7;
            int c = rem & 127;
            wl[cil][tap][c] = twl[((ch * CI_CHUNK + cil) * 9 + tap) * 512 + cot * 128 + c];
        }
        __syncthreads();

        for (int cil = 0; cil < CI_CHUNK; ++cil) {
            float xv[6][3];
#pragma unroll
            for (int rr = 0; rr < 6; ++rr) {
                xv[rr][0] = xs[rr][cil][x];
                xv[rr][1] = xs[rr][cil][x + 1];
                xv[rr][2] = xs[rr][cil][x + 2];
            }
#pragma unroll
            for (int ky = 0; ky < 3; ++ky) {
#pragma unroll
                for (int kx = 0; kx < 3; ++kx) {
                    const float4* wp = reinterpret_cast<const float4*>(&wl[cil][ky * 3 + kx][cg * 16]);
                    float4 wa = wp[0], wb = wp[1], wc = wp[2], wd = wp[3];
#pragma unroll
                    for (int yy = 0; yy < 4; ++yy) {
                        float xvv = xv[yy + ky][kx];
                        acc[yy][0]  += xvv * wa.x; acc[yy][1]  += xvv * wa.y;
                        acc[yy][2]  += xvv * wa.z; acc[yy][3]  += xvv * wa.w;
                        acc[yy][4]  += xvv * wb.x; acc[yy][5]  += xvv * wb.y;
                        acc[yy][6]  += xvv * wb.z; acc[yy][7]  += xvv * wb.w;
                        acc[yy][8]  += xvv * wc.x; acc[yy][9]  += xvv * wc.y;
                        acc[yy][10] += xvv * wc.z; acc[yy][11] += xvv * wc.w;
                        acc[yy][12] += xvv * wd.x; acc[yy][13] += xvv * wd.y;
                        acc[yy][14] += xvv * wd.z; acc[yy][15] += xvv * wd.w;
                    }
                }
            }
        }
    }
    // write bf16 p[n][co4][y][x]
#pragma unroll
    for (int yy = 0; yy < 4; ++yy) {
#pragma unroll
        for (int j = 0; j < 16; ++j) {
            p[((n * 512 + co_base + j) * 32 + (y0 + yy)) * 32 + x] = f2bf(acc[yy][j]);
        }
    }
}

// ---------------- kernel 3: BN stats -> affine coefs ----------------
// one block per channel c in [0,128); ab[2c]=A, ab[2c+1]=B, T = A*p + B
__global__ __launch_bounds__(256) void k_stats(const unsigned short* __restrict__ pp,
                                               const float* __restrict__ gamma,
                                               const float* __restrict__ beta,
                                               float* __restrict__ ab) {
    int c = blockIdx.x;
    int tid = threadIdx.x;
    float s = 0.f, s2 = 0.f;
    for (int t = tid; t < 32768; t += 256) {   // groups of 8 bf16
        int idx8 = t << 3;
        int nn = idx8 >> 12;
        int rem = idx8 & 4095;
        int co4 = (c << 2) + (rem >> 10);
        int pos = rem & 1023;
        const uint4* src = reinterpret_cast<const uint4*>(pp + (((nn << 9) + co4) << 10) + pos);
        uint4 d = *src;
        float f;
        f = bf2f(d.x & 0xffffu); s += f; s2 += f * f;
        f = bf2f(d.x >> 16);     s += f; s2 += f * f;
        f = bf2f(d.y & 0xffffu); s += f; s2 += f * f;
        f = bf2f(d.y >> 16);     s += f; s2 += f * f;
        f = bf2f(d.z & 0xffffu); s += f; s2 += f * f;
        f = bf2f(d.z >> 16);     s += f; s2 += f * f;
        f = bf2f(d.w & 0xffffu); s += f; s2 += f * f;
        f = bf2f(d.w >> 16);     s += f; s2 += f * f;
    }
#pragma unroll
    for (int m = 1; m < 64; m <<= 1) {
        s  += __shfl_xor(s, m);
        s2 += __shfl_xor(s2, m);
    }
    __shared__ float rs[4], rs2[4];
    int wave = tid >> 6, lane = tid & 63;
    if (lane == 0) { rs[wave] = s; rs2[wave] = s2; }
    __syncthreads();
    if (tid == 0) {
        float S = rs[0] + rs[1] + rs[2] + rs[3];
        float S2 = rs2[0] + rs2[1] + rs2[2] + rs2[3];
        float mean = S * (1.f / 262144.f);
        float var = S2 * (1.f / 262144.f) - mean * mean;
        float A = gamma[c] * rsqrtf(var + 1e-5f);
        ab[2 * c] = A;
        ab[2 * c + 1] = beta[c] - mean * A;
    }
}

// ---------------- kernel 4: fused routing + entropy ----------------
// block per (b, r, y) = 1024 blocks, 256 threads (4 waves)
// lane = i*8 + oc ; per position: T[i][oc][od] in regs, shuffles for reductions
__global__ __launch_bounds__(256) void k_route(const unsigned short* __restrict__ pp,
                                               const float* __restrict__ ab,
                                               float* __restrict__ out,
                                               float* __restrict__ ent_out) {
    int bid = blockIdx.x;
    int y = bid & 31, r = (bid >> 5) & 3, b = bid >> 7;
    int tid = threadIdx.x;
    int wave = tid >> 6, lane = tid & 63;
    int i_l = lane >> 3, oc_l = lane & 7;

    __shared__ unsigned short Tl[16][16][64];  // [od][x][lane] 32 KB
    __shared__ float vst[8][16][16];           // [oc][od][x]    8 KB
    __shared__ float ered[4];

    float Ac[16], Bc[16];
#pragma unroll
    for (int od = 0; od < 16; ++od) {
        Ac[od] = ab[2 * (oc_l * 16 + od)];
        Bc[od] = ab[2 * (oc_l * 16 + od) + 1];
    }

    float e_sum = 0.f;

    for (int chunk = 0; chunk < 2; ++chunk) {
        int x0 = chunk * 16;
        __syncthreads();
        // load 16-x slice of preds into LDS, transposed
        for (int pass = 0; pass < 4; ++pass) {
            int od = wave + pass * 4;   // uniform per wave
            int ii = lane >> 3, oo = lane & 7;
            int n = b * 8 + ii;
            int co4 = (oo * 16 + od) * 4 + r;
            const uint4* src = reinterpret_cast<const uint4*>(pp + ((n * 512 + co4) * 32 + y) * 32 + x0);
            uint4 da = src[0], db = src[1];
            Tl[od][0][lane]  = (unsigned short)(da.x & 0xffffu);
            Tl[od][1][lane]  = (unsigned short)(da.x >> 16);
            Tl[od][2][lane]  = (unsigned short)(da.y & 0xffffu);
            Tl[od][3][lane]  = (unsigned short)(da.y >> 16);
            Tl[od][4][lane]  = (unsigned short)(da.z & 0xffffu);
            Tl[od][5][lane]  = (unsigned short)(da.z >> 16);
            Tl[od][6][lane]  = (unsigned short)(da.w & 0xffffu);
            Tl[od][7][lane]  = (unsigned short)(da.w >> 16);
            Tl[od][8][lane]  = (unsigned short)(db.x & 0xffffu);
            Tl[od][9][lane]  = (unsigned short)(db.x >> 16);
            Tl[od][10][lane] = (unsigned short)(db.y & 0xffffu);
            Tl[od][11][lane] = (unsigned short)(db.y >> 16);
            Tl[od][12][lane] = (unsigned short)(db.z & 0xffffu);
            Tl[od][13][lane] = (unsigned short)(db.z >> 16);
            Tl[od][14][lane] = (unsigned short)(db.w & 0xffffu);
            Tl[od][15][lane] = (unsigned short)(db.w >> 16);
        }
        __syncthreads();

        for (int pi = 0; pi < 4; ++pi) {
            int px = wave * 4 + pi;
            float t[16];
#pragma unroll
            for (int od = 0; od < 16; ++od)
                t[od] = Ac[od] * bf2f((unsigned int)Tl[od][px][lane]) + Bc[od];

            float bij = 0.f, c = 0.125f, scale = 0.f;
            float s[16];
            for (int it = 0; it < 3; ++it) {
                // softmax over oc (lanes differing in bits 0..2)
                float m = bij;
                m = fmaxf(m, __shfl_xor(m, 1));
                m = fmaxf(m, __shfl_xor(m, 2));
                m = fmaxf(m, __shfl_xor(m, 4));
                float e = expf(bij - m);
                float se = e;
                se += __shfl_xor(se, 1);
                se += __shfl_xor(se, 2);
                se += __shfl_xor(se, 4);
                c = e / se;
                // s[od] = sum_i c * t[od]  (lanes differing in bits 3..5)
#pragma unroll
                for (int od = 0; od < 16; ++od) s[od] = c * t[od];
#pragma unroll
                for (int od = 0; od < 16; ++od) s[od] += __shfl_xor(s[od], 8);
#pragma unroll
                for (int od = 0; od < 16; ++od) s[od] += __shfl_xor(s[od], 16);
#pragma unroll
                for (int od = 0; od < 16; ++od) s[od] += __shfl_xor(s[od], 32);
                // squash
                float n2 = 0.f;
#pragma unroll
                for (int od = 0; od < 16; ++od) n2 += s[od] * s[od];
                float nrm = sqrtf(n2);
                scale = n2 / ((1.f + n2) * (nrm + 1e-8f));
                if (it < 2) {
                    float a = 0.f;
#pragma unroll
                    for (int od = 0; od < 16; ++od) a += t[od] * s[od];
                    bij += a * scale;
                }
            }
            // entropy: every lane has a distinct (i, oc)
            e_sum += -c * logf(c);
            // write v (identical across i lanes)
            if (i_l == 0) {
#pragma unroll
                for (int od = 0; od < 16; ++od) vst[oc_l][od][px] = scale * s[od];
            }
        }
        __syncthreads();
        // coalesced v output: out[b][oc][od][r][y][x]
        {
            int xx = tid & 15, od = (tid >> 4) & 15;
            for (int oc = 0; oc < 8; ++oc) {
                out[((((b * 8 + oc) * 16 + od) * 4 + r) * 32 + y) * 32 + x0 + xx] = vst[oc][od][xx];
            }
        }
    }

    // entropy reduction
#pragma unroll
    for (int m = 1; m < 64; m <<= 1) e_sum += __shfl_xor(e_sum, m);
    if (lane == 0) ered[wave] = e_sum;
    __syncthreads();
    if (tid == 0) {
        float tot = ered[0] + ered[1] + ered[2] + ered[3];
        atomicAdd(ent_out, tot * (1.0f / (2.0794415416798357f * 32768.0f)));
    }
}

extern "C" void kernel_launch(void* const* d_in, const int* in_sizes, int n_in,
                              void* d_out, int out_size, void* d_ws, size_t ws_size,
                              hipStream_t stream) {
    const float* x     = (const float*)d_in[0];  // (8,8,16,4,32,32)
    const float* w     = (const float*)d_in[1];  // (128,16,4,3,3)
    const float* gamma = (const float*)d_in[2];  // (128)
    const float* beta  = (const float*)d_in[3];  // (128)
    float* out = (float*)d_out;                  // 4,194,304 v + 1 entropy

    char* ws = (char*)d_ws;
    float* twl          = (float*)ws;                         // 1,179,648 B
    unsigned short* p   = (unsigned short*)(ws + 1179648);    // 67,108,864 B
    float* ab           = (float*)(ws + 1179648 + 67108864);  // 1 KB
    // total ws need ~65.2 MiB

    // zero the entropy accumulator slot (v region is fully overwritten each call)
    hipMemsetAsync(out + 4194304, 0, 4, stream);

    k_tw<<<1152, 256, 0, stream>>>(w, twl);

    dim3 gconv(64, 8, 4);
    k_conv<<<gconv, 256, 0, stream>>>(x, twl, p);

    k_stats<<<128, 256, 0, stream>>>(p, gamma, beta, ab);

    k_route<<<1024, 256, 0, stream>>>(p, ab, out, out + 4194304);
}

// Round 4
// 210.416 us; speedup vs baseline: 3.0315x; 3.0315x over previous
//
#include <hip/hip_runtime.h>
#include <hip/hip_bf16.h>

// B=8 IC=8 ID=16 OC=8 OD=16 H=W=32 K=3 ITER=3
// conv as MFMA GEMM per image: A=tw (512 co4 x 576 k), B=im2col(x) (576 k x 1024 pos)
// k = tap*64 + ci4.  p (64, 512, 32, 32) bf16.  Routing per (b, r, y, x).
// v output: (B, OC, OD, 4, H, W) = 4,194,304 fp32; entropy scalar at out[4194304]

typedef short bf16x8 __attribute__((ext_vector_type(8)));
typedef float f32x4 __attribute__((ext_vector_type(4)));

__device__ inline float bf2f(unsigned int u) {
    union { unsigned int i; float f; } x;
    x.i = u << 16;
    return x.f;
}
__device__ inline unsigned short f2bf(float f) {
    union { float f; unsigned int u; } x;
    x.f = f;
    unsigned int r = x.u + 0x7fffu + ((x.u >> 16) & 1u);
    return (unsigned short)(r >> 16);
}

// ---------------- kernel 1: transformed weights, bf16, pre-swizzled ----------------
// twb[tap][co4][ci'] : [9][512][64] bf16 ; stored ci' = ci ^ ((co4&7)<<3)
__global__ __launch_bounds__(256) void k_twb(const float* __restrict__ w,
                                             unsigned short* __restrict__ twb) {
    int idx = blockIdx.x * 256 + threadIdx.x;   // 1152 blocks * 256 = 294912 exactly
    int tap = idx >> 15;
    int rem = idx & 32767;
    int co4 = rem >> 6;
    int cst = rem & 63;
    int ci = cst ^ ((co4 & 7) << 3);            // logical ci index (ci_cap*4 + s)
    int r = co4 & 3, co = co4 >> 2;
    int s = ci & 3, cicap = ci >> 2;
    int ky = tap / 3, kx = tap % 3;
    int sy, sx;
    switch (r) {
        case 0: sy = ky;      sx = kx;      break;
        case 1: sy = kx;      sx = 2 - ky;  break;
        case 2: sy = 2 - ky;  sx = 2 - kx;  break;
        default: sy = 2 - kx; sx = ky;      break;
    }
    int ss = (s - r) & 3;
    twb[idx] = f2bf(w[(((co * 16 + cicap) * 4 + ss) * 3 + sy) * 3 + sx]);
}

// ---------------- kernel 2: pad + transpose + bf16 + swizzle the input ----------------
// xpad[n][yy][xx][ci'] : [64][34][34][64] bf16 ; stored ci' = ci ^ ((xx&7)<<3)
__global__ __launch_bounds__(256) void k_prep(const float* __restrict__ xf,
                                              unsigned short* __restrict__ xpad) {
    int n = blockIdx.x / 34, yy = blockIdx.x % 34;
    int y = yy - 1;
    unsigned short* dst = xpad + (n * 34 + yy) * 2176;
    for (int t = threadIdx.x; t < 34 * 8; t += 256) {
        int xx = t >> 3, g = t & 7;
        int x = xx - 1;
        unsigned short vals[8];
        if ((unsigned)y < 32u && (unsigned)x < 32u) {
            int lg = g ^ (xx & 7);
#pragma unroll
            for (int j = 0; j < 8; ++j)
                vals[j] = f2bf(xf[((n * 64 + lg * 8 + j) * 32 + y) * 32 + x]);
        } else {
#pragma unroll
            for (int j = 0; j < 8; ++j) vals[j] = 0;
        }
        uint4 pk;
        pk.x = (unsigned)vals[0] | ((unsigned)vals[1] << 16);
        pk.y = (unsigned)vals[2] | ((unsigned)vals[3] << 16);
        pk.z = (unsigned)vals[4] | ((unsigned)vals[5] << 16);
        pk.w = (unsigned)vals[6] | ((unsigned)vals[7] << 16);
        *reinterpret_cast<uint4*>(&dst[xx * 64 + g * 8]) = pk;
    }
}

// ---------------- kernel 3: MFMA conv ----------------
// grid (64 n, 8 yt, 4 cot), 256 threads = 4 waves in 2x2 (M x N)
// wave tile: 64 co4 x 64 pos (4x4 fragments of 16x16), K = 18 steps of 32
__global__ __launch_bounds__(256) void k_mconv(const unsigned short* __restrict__ xpad,
                                               const unsigned short* __restrict__ twb,
                                               unsigned short* __restrict__ p) {
    int n = blockIdx.x, yt = blockIdx.y, cot = blockIdx.z;
    int y0 = yt * 4;
    int tid = threadIdx.x, lane = tid & 63, wave = tid >> 6;
    int wm = (wave >> 1) * 64, wn = (wave & 1) * 64;
    int p15 = lane & 15, hi = lane >> 4;

    __shared__ unsigned short xs[6 * 34 * 64];   // [row][xx][ci'] 26112 B
    __shared__ unsigned short wA[128 * 64];      // [co4l][ci']    16384 B

    // stage 6 padded image rows y0..y0+5, one linear copy (pre-swizzled in global)
    {
        const uint4* src = reinterpret_cast<const uint4*>(xpad + (n * 34 + y0) * 2176);
        uint4* dst = reinterpret_cast<uint4*>(xs);
        for (int t = tid; t < 1632; t += 256) dst[t] = src[t];
    }

    f32x4 acc[4][4];
#pragma unroll
    for (int mf = 0; mf < 4; ++mf)
#pragma unroll
        for (int nf = 0; nf < 4; ++nf) acc[mf][nf] = (f32x4){0.f, 0.f, 0.f, 0.f};

    int yl[4], xb[4];
#pragma unroll
    for (int nf = 0; nf < 4; ++nf) {
        int posl = wn + nf * 16 + p15;
        yl[nf] = posl >> 5;
        xb[nf] = posl & 31;
    }

    for (int tap = 0; tap < 9; ++tap) {
        __syncthreads();   // xs ready (tap 0) / previous tap's wA reads done
        {
            const uint4* wsrc = reinterpret_cast<const uint4*>(twb + (tap * 512 + cot * 128) * 64);
            uint4* wdst = reinterpret_cast<uint4*>(wA);
            for (int t = tid; t < 1024; t += 256) wdst[t] = wsrc[t];  // 128co4 x 64ci = 1024 uint4
        }
        __syncthreads();

        int ky = tap / 3, kx = tap % 3;

        bf16x8 a[4][2], b[4][2];
#pragma unroll
        for (int mf = 0; mf < 4; ++mf) {
            int co4l = wm + mf * 16 + p15;
#pragma unroll
            for (int s = 0; s < 2; ++s) {
                int cig = hi + s * 4;
                a[mf][s] = *reinterpret_cast<const bf16x8*>(
                    &wA[co4l * 64 + ((cig ^ (co4l & 7)) << 3)]);
            }
        }
#pragma unroll
        for (int nf = 0; nf < 4; ++nf) {
            int row = yl[nf] + ky, col = xb[nf] + kx;
#pragma unroll
            for (int s = 0; s < 2; ++s) {
                int cig = hi + s * 4;
                b[nf][s] = *reinterpret_cast<const bf16x8*>(
                    &xs[(row * 34 + col) * 64 + ((cig ^ (col & 7)) << 3)]);
            }
        }
#pragma unroll
        for (int s = 0; s < 2; ++s)
#pragma unroll
            for (int mf = 0; mf < 4; ++mf)
#pragma unroll
                for (int nf = 0; nf < 4; ++nf)
                    acc[mf][nf] = __builtin_amdgcn_mfma_f32_16x16x32_bf16(
                        a[mf][s], b[nf][s], acc[mf][nf], 0, 0, 0);
    }

    // write p[n][co4][y][x] bf16; C layout: col=lane&15 -> pos, row=hi*4+reg -> co4
#pragma unroll
    for (int mf = 0; mf < 4; ++mf)
#pragma unroll
        for (int nf = 0; nf < 4; ++nf) {
            int posl = wn + nf * 16 + p15;
            int y = y0 + (posl >> 5), x = posl & 31;
#pragma unroll
            for (int reg = 0; reg < 4; ++reg) {
                int co4 = cot * 128 + wm + mf * 16 + hi * 4 + reg;
                p[((n * 512 + co4) * 32 + y) * 32 + x] = f2bf(acc[mf][nf][reg]);
            }
        }
}

// ---------------- kernel 4: BN stats -> affine coefs ----------------
__global__ __launch_bounds__(256) void k_stats(const unsigned short* __restrict__ pp,
                                               const float* __restrict__ gamma,
                                               const float* __restrict__ beta,
                                               float* __restrict__ ab) {
    int c = blockIdx.x;
    int tid = threadIdx.x;
    float s = 0.f, s2 = 0.f;
    for (int t = tid; t < 32768; t += 256) {
        int idx8 = t << 3;
        int nn = idx8 >> 12;
        int rem = idx8 & 4095;
        int co4 = (c << 2) + (rem >> 10);
        int pos = rem & 1023;
        const uint4* src = reinterpret_cast<const uint4*>(pp + (((nn << 9) + co4) << 10) + pos);
        uint4 d = *src;
        float f;
        f = bf2f(d.x & 0xffffu); s += f; s2 += f * f;
        f = bf2f(d.x >> 16);     s += f; s2 += f * f;
        f = bf2f(d.y & 0xffffu); s += f; s2 += f * f;
        f = bf2f(d.y >> 16);     s += f; s2 += f * f;
        f = bf2f(d.z & 0xffffu); s += f; s2 += f * f;
        f = bf2f(d.z >> 16);     s += f; s2 += f * f;
        f = bf2f(d.w & 0xffffu); s += f; s2 += f * f;
        f = bf2f(d.w >> 16);     s += f; s2 += f * f;
    }
#pragma unroll
    for (int m = 1; m < 64; m <<= 1) {
        s  += __shfl_xor(s, m);
        s2 += __shfl_xor(s2, m);
    }
    __shared__ float rs[4], rs2[4];
    int wave = tid >> 6, lane = tid & 63;
    if (lane == 0) { rs[wave] = s; rs2[wave] = s2; }
    __syncthreads();
    if (tid == 0) {
        float S = rs[0] + rs[1] + rs[2] + rs[3];
        float S2 = rs2[0] + rs2[1] + rs2[2] + rs2[3];
        float mean = S * (1.f / 262144.f);
        float var = S2 * (1.f / 262144.f) - mean * mean;
        float A = gamma[c] * rsqrtf(var + 1e-5f);
        ab[2 * c] = A;
        ab[2 * c + 1] = beta[c] - mean * A;
    }
}

// ---------------- kernel 5: fused routing + entropy ----------------
__global__ __launch_bounds__(256) void k_route(const unsigned short* __restrict__ pp,
                                               const float* __restrict__ ab,
                                               float* __restrict__ out,
                                               float* __restrict__ ent_out) {
    int bid = blockIdx.x;
    int y = bid & 31, r = (bid >> 5) & 3, b = bid >> 7;
    int tid = threadIdx.x;
    int wave = tid >> 6, lane = tid & 63;
    int i_l = lane >> 3, oc_l = lane & 7;

    __shared__ unsigned short Tl[16][16][64];  // [od][x][lane] 32 KB
    __shared__ float vst[8][16][16];           // [oc][od][x]    8 KB
    __shared__ float ered[4];

    float Ac[16], Bc[16];
#pragma unroll
    for (int od = 0; od < 16; ++od) {
        Ac[od] = ab[2 * (oc_l * 16 + od)];
        Bc[od] = ab[2 * (oc_l * 16 + od) + 1];
    }

    float e_sum = 0.f;

    for (int chunk = 0; chunk < 2; ++chunk) {
        int x0 = chunk * 16;
        __syncthreads();
        for (int pass = 0; pass < 4; ++pass) {
            int od = wave + pass * 4;
            int ii = lane >> 3, oo = lane & 7;
            int n = b * 8 + ii;
            int co4 = (oo * 16 + od) * 4 + r;
            const uint4* src = reinterpret_cast<const uint4*>(pp + ((n * 512 + co4) * 32 + y) * 32 + x0);
            uint4 da = src[0], db = src[1];
            Tl[od][0][lane]  = (unsigned short)(da.x & 0xffffu);
            Tl[od][1][lane]  = (unsigned short)(da.x >> 16);
            Tl[od][2][lane]  = (unsigned short)(da.y & 0xffffu);
            Tl[od][3][lane]  = (unsigned short)(da.y >> 16);
            Tl[od][4][lane]  = (unsigned short)(da.z & 0xffffu);
            Tl[od][5][lane]  = (unsigned short)(da.z >> 16);
            Tl[od][6][lane]  = (unsigned short)(da.w & 0xffffu);
            Tl[od][7][lane]  = (unsigned short)(da.w >> 16);
            Tl[od][8][lane]  = (unsigned short)(db.x & 0xffffu);
            Tl[od][9][lane]  = (unsigned short)(db.x >> 16);
            Tl[od][10][lane] = (unsigned short)(db.y & 0xffffu);
            Tl[od][11][lane] = (unsigned short)(db.y >> 16);
            Tl[od][12][lane] = (unsigned short)(db.z & 0xffffu);
            Tl[od][13][lane] = (unsigned short)(db.z >> 16);
            Tl[od][14][lane] = (unsigned short)(db.w & 0xffffu);
            Tl[od][15][lane] = (unsigned short)(db.w >> 16);
        }
        __syncthreads();

        for (int pi = 0; pi < 4; ++pi) {
            int px = wave * 4 + pi;
            float t[16];
#pragma unroll
            for (int od = 0; od < 16; ++od)
                t[od] = Ac[od] * bf2f((unsigned int)Tl[od][px][lane]) + Bc[od];

            float bij = 0.f, c = 0.125f, scale = 0.f;
            float s[16];
            for (int it = 0; it < 3; ++it) {
                float m = bij;
                m = fmaxf(m, __shfl_xor(m, 1));
                m = fmaxf(m, __shfl_xor(m, 2));
                m = fmaxf(m, __shfl_xor(m, 4));
                float e = expf(bij - m);
                float se = e;
                se += __shfl_xor(se, 1);
                se += __shfl_xor(se, 2);
                se += __shfl_xor(se, 4);
                c = e / se;
#pragma unroll
                for (int od = 0; od < 16; ++od) s[od] = c * t[od];
#pragma unroll
                for (int od = 0; od < 16; ++od) s[od] += __shfl_xor(s[od], 8);
#pragma unroll
                for (int od = 0; od < 16; ++od) s[od] += __shfl_xor(s[od], 16);
#pragma unroll
                for (int od = 0; od < 16; ++od) s[od] += __shfl_xor(s[od], 32);
                float n2 = 0.f;
#pragma unroll
                for (int od = 0; od < 16; ++od) n2 += s[od] * s[od];
                float nrm = sqrtf(n2);
                scale = n2 / ((1.f + n2) * (nrm + 1e-8f));
                if (it < 2) {
                    float a = 0.f;
#pragma unroll
                    for (int od = 0; od < 16; ++od) a += t[od] * s[od];
                    bij += a * scale;
                }
            }
            e_sum += -c * logf(c);
            if (i_l == 0) {
#pragma unroll
                for (int od = 0; od < 16; ++od) vst[oc_l][od][px] = scale * s[od];
            }
        }
        __syncthreads();
        {
            int xx = tid & 15, od = (tid >> 4) & 15;
            for (int oc = 0; oc < 8; ++oc) {
                out[((((b * 8 + oc) * 16 + od) * 4 + r) * 32 + y) * 32 + x0 + xx] = vst[oc][od][xx];
            }
        }
    }

#pragma unroll
    for (int m = 1; m < 64; m <<= 1) e_sum += __shfl_xor(e_sum, m);
    if (lane == 0) ered[wave] = e_sum;
    __syncthreads();
    if (tid == 0) {
        float tot = ered[0] + ered[1] + ered[2] + ered[3];
        atomicAdd(ent_out, tot * (1.0f / (2.0794415416798357f * 32768.0f)));
    }
}

extern "C" void kernel_launch(void* const* d_in, const int* in_sizes, int n_in,
                              void* d_out, int out_size, void* d_ws, size_t ws_size,
                              hipStream_t stream) {
    const float* x     = (const float*)d_in[0];  // (8,8,16,4,32,32)
    const float* w     = (const float*)d_in[1];  // (128,16,4,3,3)
    const float* gamma = (const float*)d_in[2];  // (128)
    const float* beta  = (const float*)d_in[3];  // (128)
    float* out = (float*)d_out;                  // 4,194,304 v + 1 entropy

    char* ws = (char*)d_ws;
    unsigned short* p    = (unsigned short*)ws;                        // 67,108,864 B
    unsigned short* xpad = (unsigned short*)(ws + 67108864);           //  9,469,952 B
    unsigned short* twb  = (unsigned short*)(ws + 67108864 + 9469952); //    589,824 B
    float* ab            = (float*)(ws + 67108864 + 9469952 + 589824); //      1,024 B

    hipMemsetAsync(out + 4194304, 0, 4, stream);

    k_twb<<<1152, 256, 0, stream>>>(w, twb);
    k_prep<<<64 * 34, 256, 0, stream>>>(x, xpad);

    dim3 gconv(64, 8, 4);
    k_mconv<<<gconv, 256, 0, stream>>>(xpad, twb, p);

    k_stats<<<128, 256, 0, stream>>>(p, gamma, beta, ab);

    k_route<<<1024, 256, 0, stream>>>(p, ab, out, out + 4194304);
}

// Round 5
// 145.252 us; speedup vs baseline: 4.3915x; 1.4486x over previous
//
#include <hip/hip_runtime.h>
#include <hip/hip_bf16.h>

// B=8 IC=8 ID=16 OC=8 OD=16 H=W=32 K=3 ITER=3
// conv as MFMA GEMM per image: A=tw (512 co4 x 576 k), B=im2col(x) (576 k x 1024 pos)
// p (64, 512, 32, 32) bf16.  Routing per (b, r, y, x).
// v output: (B, OC, OD, 4, H, W) = 4,194,304 fp32; entropy scalar at out[4194304]

typedef short bf16x8 __attribute__((ext_vector_type(8)));
typedef float f32x4 __attribute__((ext_vector_type(4)));
typedef unsigned int u32x2 __attribute__((ext_vector_type(2)));

__device__ inline float bf2f(unsigned int u) {
    union { unsigned int i; float f; } x;
    x.i = u << 16;
    return x.f;
}
__device__ inline unsigned short f2bf(float f) {
    union { float f; unsigned int u; } x;
    x.f = f;
    unsigned int r = x.u + 0x7fffu + ((x.u >> 16) & 1u);
    return (unsigned short)(r >> 16);
}

// cross-lane helpers (all-lanes-active contexts only)
__device__ inline float dppx1(float x) {   // lane ^ 1 (quad_perm 1,0,3,2)
    return __int_as_float(__builtin_amdgcn_update_dpp(0, __float_as_int(x), 0xB1, 0xF, 0xF, false));
}
__device__ inline float dppx2(float x) {   // lane ^ 2 (quad_perm 2,3,0,1)
    return __int_as_float(__builtin_amdgcn_update_dpp(0, __float_as_int(x), 0x4E, 0xF, 0xF, false));
}
template <int PATT>
__device__ inline float swzf(float x) {    // ds_swizzle xor pattern
    return __int_as_float(__builtin_amdgcn_ds_swizzle(__float_as_int(x), PATT));
}
#define SWZ4  0x101F
#define SWZ8  0x201F
#define SWZ16 0x401F
__device__ inline float psum32(float x) {  // x + x[lane^32] via permlane32_swap (conv-immune)
    u32x2 r = __builtin_amdgcn_permlane32_swap(__float_as_uint(x), __float_as_uint(x), false, false);
    return __uint_as_float(r[0]) + __uint_as_float(r[1]);
}

// ---------------- kernel 1: transformed weights, bf16, pre-swizzled ----------------
// twb[tap][co4][ci'] : [9][512][64] bf16 ; stored ci' = ci ^ ((co4&7)<<3)
__global__ __launch_bounds__(256) void k_twb(const float* __restrict__ w,
                                             unsigned short* __restrict__ twb) {
    int idx = blockIdx.x * 256 + threadIdx.x;
    int tap = idx >> 15;
    int rem = idx & 32767;
    int co4 = rem >> 6;
    int cst = rem & 63;
    int ci = cst ^ ((co4 & 7) << 3);
    int r = co4 & 3, co = co4 >> 2;
    int s = ci & 3, cicap = ci >> 2;
    int ky = tap / 3, kx = tap % 3;
    int sy, sx;
    switch (r) {
        case 0: sy = ky;      sx = kx;      break;
        case 1: sy = kx;      sx = 2 - ky;  break;
        case 2: sy = 2 - ky;  sx = 2 - kx;  break;
        default: sy = 2 - kx; sx = ky;      break;
    }
    int ss = (s - r) & 3;
    twb[idx] = f2bf(w[(((co * 16 + cicap) * 4 + ss) * 3 + sy) * 3 + sx]);
}

// ---------------- kernel 2: pad + transpose + bf16 + swizzle the input ----------------
// xpad[n][yy][xx][ci'] : [64][34][34][64] bf16 ; ci' = ci ^ ((xx&7)<<3); borders pre-zeroed by memset
__global__ __launch_bounds__(256) void k_prep(const float* __restrict__ xf,
                                              unsigned short* __restrict__ xpad) {
    int n = blockIdx.x >> 5, y = blockIdx.x & 31;
    int tid = threadIdx.x;
    __shared__ float tile[64][33];
#pragma unroll
    for (int it = 0; it < 8; ++it) {
        int ci = it * 8 + (tid >> 5), x = tid & 31;
        tile[ci][x] = xf[((n * 64 + ci) * 32 + y) * 32 + x];   // coalesced 128B
    }
    __syncthreads();
    int xx = 1 + (tid >> 3), g = tid & 7;
    int x = xx - 1;
    int lg = g ^ (xx & 7);
    unsigned short vals[8];
#pragma unroll
    for (int j = 0; j < 8; ++j) vals[j] = f2bf(tile[lg * 8 + j][x]);
    uint4 pk;
    pk.x = (unsigned)vals[0] | ((unsigned)vals[1] << 16);
    pk.y = (unsigned)vals[2] | ((unsigned)vals[3] << 16);
    pk.z = (unsigned)vals[4] | ((unsigned)vals[5] << 16);
    pk.w = (unsigned)vals[6] | ((unsigned)vals[7] << 16);
    *reinterpret_cast<uint4*>(&xpad[(n * 34 + (y + 1)) * 2176 + xx * 64 + g * 8]) = pk;
}

// ---------------- kernel 3: MFMA conv (unchanged) ----------------
__global__ __launch_bounds__(256) void k_mconv(const unsigned short* __restrict__ xpad,
                                               const unsigned short* __restrict__ twb,
                                               unsigned short* __restrict__ p) {
    int n = blockIdx.x, yt = blockIdx.y, cot = blockIdx.z;
    int y0 = yt * 4;
    int tid = threadIdx.x, lane = tid & 63, wave = tid >> 6;
    int wm = (wave >> 1) * 64, wn = (wave & 1) * 64;
    int p15 = lane & 15, hi = lane >> 4;

    __shared__ unsigned short xs[6 * 34 * 64];
    __shared__ unsigned short wA[128 * 64];

    {
        const uint4* src = reinterpret_cast<const uint4*>(xpad + (n * 34 + y0) * 2176);
        uint4* dst = reinterpret_cast<uint4*>(xs);
        for (int t = tid; t < 1632; t += 256) dst[t] = src[t];
    }

    f32x4 acc[4][4];
#pragma unroll
    for (int mf = 0; mf < 4; ++mf)
#pragma unroll
        for (int nf = 0; nf < 4; ++nf) acc[mf][nf] = (f32x4){0.f, 0.f, 0.f, 0.f};

    int yl[4], xb[4];
#pragma unroll
    for (int nf = 0; nf < 4; ++nf) {
        int posl = wn + nf * 16 + p15;
        yl[nf] = posl >> 5;
        xb[nf] = posl & 31;
    }

    for (int tap = 0; tap < 9; ++tap) {
        __syncthreads();
        {
            const uint4* wsrc = reinterpret_cast<const uint4*>(twb + (tap * 512 + cot * 128) * 64);
            uint4* wdst = reinterpret_cast<uint4*>(wA);
            for (int t = tid; t < 1024; t += 256) wdst[t] = wsrc[t];
        }
        __syncthreads();

        int ky = tap / 3, kx = tap % 3;

        bf16x8 a[4][2], b[4][2];
#pragma unroll
        for (int mf = 0; mf < 4; ++mf) {
            int co4l = wm + mf * 16 + p15;
#pragma unroll
            for (int s = 0; s < 2; ++s) {
                int cig = hi + s * 4;
                a[mf][s] = *reinterpret_cast<const bf16x8*>(
                    &wA[co4l * 64 + ((cig ^ (co4l & 7)) << 3)]);
            }
        }
#pragma unroll
        for (int nf = 0; nf < 4; ++nf) {
            int row = yl[nf] + ky, col = xb[nf] + kx;
#pragma unroll
            for (int s = 0; s < 2; ++s) {
                int cig = hi + s * 4;
                b[nf][s] = *reinterpret_cast<const bf16x8*>(
                    &xs[(row * 34 + col) * 64 + ((cig ^ (col & 7)) << 3)]);
            }
        }
#pragma unroll
        for (int s = 0; s < 2; ++s)
#pragma unroll
            for (int mf = 0; mf < 4; ++mf)
#pragma unroll
                for (int nf = 0; nf < 4; ++nf)
                    acc[mf][nf] = __builtin_amdgcn_mfma_f32_16x16x32_bf16(
                        a[mf][s], b[nf][s], acc[mf][nf], 0, 0, 0);
    }

#pragma unroll
    for (int mf = 0; mf < 4; ++mf)
#pragma unroll
        for (int nf = 0; nf < 4; ++nf) {
            int posl = wn + nf * 16 + p15;
            int y = y0 + (posl >> 5), x = posl & 31;
#pragma unroll
            for (int reg = 0; reg < 4; ++reg) {
                int co4 = cot * 128 + wm + mf * 16 + hi * 4 + reg;
                p[((n * 512 + co4) * 32 + y) * 32 + x] = f2bf(acc[mf][nf][reg]);
            }
        }
}

// ---------------- kernel 4a: BN partial sums (512 blocks) ----------------
// block = (c, q): n-range q*16..q*16+15 ; ps[(c*4+q)*2 + {0,1}] = {sum, sumsq}
__global__ __launch_bounds__(256) void k_stats1(const unsigned short* __restrict__ pp,
                                                float* __restrict__ ps) {
    int c = blockIdx.x >> 2, q = blockIdx.x & 3;
    int tid = threadIdx.x;
    float s = 0.f, s2 = 0.f;
    for (int t = tid; t < 8192; t += 256) {
        int idx8 = t << 3;
        int nn = (q << 4) + (idx8 >> 12);
        int rem = idx8 & 4095;
        int co4 = (c << 2) + (rem >> 10);
        int pos = rem & 1023;
        uint4 d = *reinterpret_cast<const uint4*>(pp + (((nn << 9) + co4) << 10) + pos);
        float f;
        f = bf2f(d.x & 0xffffu); s += f; s2 += f * f;
        f = bf2f(d.x >> 16);     s += f; s2 += f * f;
        f = bf2f(d.y & 0xffffu); s += f; s2 += f * f;
        f = bf2f(d.y >> 16);     s += f; s2 += f * f;
        f = bf2f(d.z & 0xffffu); s += f; s2 += f * f;
        f = bf2f(d.z >> 16);     s += f; s2 += f * f;
        f = bf2f(d.w & 0xffffu); s += f; s2 += f * f;
        f = bf2f(d.w >> 16);     s += f; s2 += f * f;
    }
#pragma unroll
    for (int m = 1; m < 64; m <<= 1) {
        s  += __shfl_xor(s, m);
        s2 += __shfl_xor(s2, m);
    }
    __shared__ float rs[4], rs2[4];
    int wave = tid >> 6, lane = tid & 63;
    if (lane == 0) { rs[wave] = s; rs2[wave] = s2; }
    __syncthreads();
    if (tid == 0) {
        ps[blockIdx.x * 2]     = rs[0] + rs[1] + rs[2] + rs[3];
        ps[blockIdx.x * 2 + 1] = rs2[0] + rs2[1] + rs2[2] + rs2[3];
    }
}

// ---------------- kernel 4b: finalize affine coefs ----------------
__global__ __launch_bounds__(128) void k_ab(const float* __restrict__ ps,
                                            const float* __restrict__ gamma,
                                            const float* __restrict__ beta,
                                            float* __restrict__ ab) {
    int c = threadIdx.x;
    float S  = ps[(c * 4 + 0) * 2] + ps[(c * 4 + 1) * 2] + ps[(c * 4 + 2) * 2] + ps[(c * 4 + 3) * 2];
    float S2 = ps[(c * 4 + 0) * 2 + 1] + ps[(c * 4 + 1) * 2 + 1] + ps[(c * 4 + 2) * 2 + 1] + ps[(c * 4 + 3) * 2 + 1];
    float mean = S * (1.f / 262144.f);
    float var = S2 * (1.f / 262144.f) - mean * mean;
    float A = gamma[c] * rsqrtf(var + 1e-5f);
    ab[2 * c] = A;
    ab[2 * c + 1] = beta[c] - mean * A;
}

// ---------------- kernel 5: fused routing + entropy ----------------
// grid 2048; bid: k=bid&7, ch=(bid>>3)&1, unit=(bid>>4)*8+k  (chunk-pair shares XCD, 8 slots apart)
// unit: b = u>>7, r = (u>>5)&3, y = u&31 ; chunk covers x0 = ch*16 .. +15
// 256 threads = 4 waves; lane = (i<<3)|oc; wave w handles x-pairs {w, w+4} (pair p2 -> x = x0+2*p2+{0,1})
__global__ __launch_bounds__(256, 4) void k_route(const unsigned short* __restrict__ pp,
                                                  const float* __restrict__ ab,
                                                  float* __restrict__ out,
                                                  float* __restrict__ ent_out) {
    int bid = blockIdx.x;
    int u = ((bid >> 4) << 3) + (bid & 7);
    int ch = (bid >> 3) & 1;
    int y = u & 31, r = (u >> 5) & 3, b = u >> 7;
    int x0 = ch * 16;
    int tid = threadIdx.x;
    int wave = tid >> 6, lane = tid & 63;
    int i_l = lane >> 3, oc_l = lane & 7;

    __shared__ unsigned int Tl2[16][8][64];      // [od][x-pair][lane(i,oc)]  32 KB, bf16x2 = A*p+B
    __shared__ unsigned short vst[8][16][18];    // [oc][od][x(16)+pad]       4.5 KB
    __shared__ float ered[4];

    // ---- stage: load p, apply BN affine, pack x-pairs ----
#pragma unroll
    for (int t4i = 0; t4i < 4; ++t4i) {
        int t4 = tid + t4i * 256;
        int od = t4 >> 6, ls = t4 & 63;
        int ii = ls >> 3, oo = ls & 7;
        int c = oo * 16 + od;
        int co4 = c * 4 + r;
        int n = b * 8 + ii;
        float A = ab[2 * c], Bv = ab[2 * c + 1];
        const uint4* src = reinterpret_cast<const uint4*>(pp + ((n * 512 + co4) * 32 + y) * 32 + x0);
        uint4 d0 = src[0], d1 = src[1];
        unsigned wds[8] = {d0.x, d0.y, d0.z, d0.w, d1.x, d1.y, d1.z, d1.w};
#pragma unroll
        for (int j = 0; j < 8; ++j) {
            float tlo = A * bf2f(wds[j] & 0xffffu) + Bv;
            float thi = A * bf2f(wds[j] >> 16) + Bv;
            Tl2[od][j][ls] = (unsigned)f2bf(tlo) | ((unsigned)f2bf(thi) << 16);
        }
    }
    __syncthreads();

    float e_acc = 0.f;

    for (int q = 0; q < 2; ++q) {
        int p2 = wave + q * 4;             // x-pair index 0..7
        float t0[16], t1[16];
#pragma unroll
        for (int od = 0; od < 16; ++od) {
            unsigned pr = Tl2[od][p2][lane];
            t0[od] = bf2f(pr & 0xffffu);
            t1[od] = bf2f(pr >> 16);
        }

        float b0 = 0.f, b1 = 0.f, c0, c1, sc0 = 0.f, sc1 = 0.f;
        float s0[16], s1[16];
        for (int it = 0; it < 3; ++it) {
            // softmax over oc (lane bits 0-2)
            float m0 = b0, m1 = b1;
            m0 = fmaxf(m0, dppx1(m0));      m1 = fmaxf(m1, dppx1(m1));
            m0 = fmaxf(m0, dppx2(m0));      m1 = fmaxf(m1, dppx2(m1));
            m0 = fmaxf(m0, swzf<SWZ4>(m0)); m1 = fmaxf(m1, swzf<SWZ4>(m1));
            float e0 = __expf(b0 - m0), e1 = __expf(b1 - m1);
            float se0 = e0, se1 = e1;
            se0 += dppx1(se0);      se1 += dppx1(se1);
            se0 += dppx2(se0);      se1 += dppx2(se1);
            se0 += swzf<SWZ4>(se0); se1 += swzf<SWZ4>(se1);
            c0 = e0 * __builtin_amdgcn_rcpf(se0);
            c1 = e1 * __builtin_amdgcn_rcpf(se1);
            // s = sum_i c*t  (lane bits 3-5)
            float n20 = 0.f, n21 = 0.f;
#pragma unroll
            for (int od = 0; od < 16; ++od) {
                float v0 = c0 * t0[od], v1 = c1 * t1[od];
                v0 += swzf<SWZ8>(v0);   v1 += swzf<SWZ8>(v1);
                v0 += swzf<SWZ16>(v0);  v1 += swzf<SWZ16>(v1);
                v0 = psum32(v0);        v1 = psum32(v1);
                s0[od] = v0;            s1[od] = v1;
                n20 += v0 * v0;         n21 += v1 * v1;
            }
            float nr0 = sqrtf(n20), nr1 = sqrtf(n21);
            sc0 = n20 * __builtin_amdgcn_rcpf((1.f + n20) * (nr0 + 1e-8f));
            sc1 = n21 * __builtin_amdgcn_rcpf((1.f + n21) * (nr1 + 1e-8f));
            if (it < 2) {
                float a0 = 0.f, a1 = 0.f;
#pragma unroll
                for (int od = 0; od < 16; ++od) {
                    a0 += t0[od] * s0[od];
                    a1 += t1[od] * s1[od];
                }
                b0 += a0 * sc0;
                b1 += a1 * sc1;
            }
        }
        e_acc += -c0 * __logf(c0) - c1 * __logf(c1);
        if (i_l == 0) {
#pragma unroll
            for (int od = 0; od < 16; ++od) {
                vst[oc_l][od][2 * p2]     = f2bf(sc0 * s0[od]);
                vst[oc_l][od][2 * p2 + 1] = f2bf(sc1 * s1[od]);
            }
        }
    }

    // entropy: reduce over all 64 lanes (each lane = distinct (i,oc), 2 pairs = 4 positions)
    e_acc += dppx1(e_acc);
    e_acc += dppx2(e_acc);
    e_acc += swzf<SWZ4>(e_acc);
    e_acc += swzf<SWZ8>(e_acc);
    e_acc += swzf<SWZ16>(e_acc);
    e_acc = psum32(e_acc);
    if (lane == 0) ered[wave] = e_acc;
    __syncthreads();   // vst + ered ready

    {
        int xx = tid & 15, od = (tid >> 4) & 15;
#pragma unroll
        for (int oc = 0; oc < 8; ++oc) {
            out[((((b * 8 + oc) * 16 + od) * 4 + r) * 32 + y) * 32 + x0 + xx] =
                bf2f(vst[oc][od][xx]);
        }
    }
    if (tid == 0) {
        float tot = ered[0] + ered[1] + ered[2] + ered[3];
        atomicAdd(ent_out, tot * (1.0f / (2.0794415416798357f * 32768.0f)));
    }
}

extern "C" void kernel_launch(void* const* d_in, const int* in_sizes, int n_in,
                              void* d_out, int out_size, void* d_ws, size_t ws_size,
                              hipStream_t stream) {
    const float* x     = (const float*)d_in[0];  // (8,8,16,4,32,32)
    const float* w     = (const float*)d_in[1];  // (128,16,4,3,3)
    const float* gamma = (const float*)d_in[2];  // (128)
    const float* beta  = (const float*)d_in[3];  // (128)
    float* out = (float*)d_out;                  // 4,194,304 v + 1 entropy

    char* ws = (char*)d_ws;
    unsigned short* p    = (unsigned short*)ws;                                  // 67,108,864 B
    unsigned short* xpad = (unsigned short*)(ws + 67108864);                     //  9,469,952 B
    unsigned short* twb  = (unsigned short*)(ws + 67108864 + 9469952);           //    589,824 B
    float* ab            = (float*)(ws + 67108864 + 9469952 + 589824);           //      1,024 B
    float* ps            = (float*)(ws + 67108864 + 9469952 + 589824 + 1024);    //      4,096 B

    hipMemsetAsync(out + 4194304, 0, 4, stream);
    hipMemsetAsync(xpad, 0, 9469952, stream);

    k_twb<<<1152, 256, 0, stream>>>(w, twb);
    k_prep<<<2048, 256, 0, stream>>>(x, xpad);

    dim3 gconv(64, 8, 4);
    k_mconv<<<gconv, 256, 0, stream>>>(xpad, twb, p);

    k_stats1<<<512, 256, 0, stream>>>(p, ps);
    k_ab<<<1, 128, 0, stream>>>(ps, gamma, beta, ab);

    k_route<<<2048, 256, 0, stream>>>(p, ab, out, out + 4194304);
}